// Round 1
// baseline (316.315 us; speedup 1.0000x reference)
//
#include <hip/hip_runtime.h>
#include <math.h>

#define G      104
#define NBA    9
#define NC     80
#define NBOX   (G*G*NBA)      // 97344
#define CH     (5+NC)         // 85
#define DET_T_ 0.02f
#define NMS_T_ 0.3f
#define MAXB   50
#define CAP    2048
#define IMG    832

__device__ __forceinline__ float sigmoidf_(float x) { return 1.0f / (1.0f + expf(-x)); }

// ---------------- decode + per-class compaction ----------------
__global__ void decode_kernel(const float* __restrict__ in, const float* __restrict__ anchors,
                              int* __restrict__ cnt, float4* __restrict__ candBox,
                              float* __restrict__ candScore, int* __restrict__ candIdx)
{
    int n = blockIdx.x * blockDim.x + threadIdx.x;
    if (n >= NBOX) return;
    const float* p = in + (size_t)n * CH;

    // softmax over p[5..84], replicate jax.nn.softmax: exp(x - max) / sum
    float m = -INFINITY;
    for (int i = 0; i < NC; ++i) m = fmaxf(m, p[5 + i]);
    float sum = 0.0f;
    for (int i = 0; i < NC; ++i) sum += expf(p[5 + i] - m);
    float obj = sigmoidf_(p[4]);

    // first-max argmax over s_i = obj * (e_i / sum)  (exact reference op order)
    float best = -1.0f; int bcls = 0;
    for (int i = 0; i < NC; ++i) {
        float e = expf(p[5 + i] - m);
        float s = obj * (e / sum);
        if (s > best) { best = s; bcls = i; }
    }

    if (best > DET_T_) {   // strict, matches scores_all > DET_T
        int a  = n % NBA;
        int t  = n / NBA;
        int gx = t % G;
        int gy = t / G;
        float bx = (sigmoidf_(p[0]) + (float)gx) / (float)G;
        float by = (sigmoidf_(p[1]) + (float)gy) / (float)G;
        float bw = expf(p[2]) * anchors[2*a + 0] / (float)G;
        float bh = expf(p[3]) * anchors[2*a + 1] / (float)G;
        float4 box = make_float4(bx - bw / 2.0f, by - bh / 2.0f,
                                 bx + bw / 2.0f, by + bh / 2.0f);
        int pos = atomicAdd(&cnt[bcls], 1);
        if (pos < CAP) {
            int slot = bcls * CAP + pos;
            candBox[slot]   = box;
            candScore[slot] = best;
            candIdx[slot]   = n;
        }
    }
}

// ---------------- per-class greedy NMS (one block per class) ----------------
__global__ __launch_bounds__(256) void nms_kernel(const int* __restrict__ cnt,
    const float4* __restrict__ candBox, const float* __restrict__ candScore,
    const int* __restrict__ candIdx, float4* __restrict__ selBox, int* __restrict__ selValid)
{
    __shared__ float  s_sc[CAP];
    __shared__ float4 s_bx[CAP];
    __shared__ int    s_id[CAP];
    __shared__ float  red_s[4];
    __shared__ int    red_i[4], red_sl[4];
    __shared__ float4 g_box;
    __shared__ int    g_idx, g_stop;

    int c = blockIdx.x;
    int count = cnt[c]; if (count > CAP) count = CAP;

    for (int i = threadIdx.x; i < CAP; i += blockDim.x) {
        if (i < count) {
            s_sc[i] = candScore[c*CAP + i];
            s_bx[i] = candBox[c*CAP + i];
            s_id[i] = candIdx[c*CAP + i];
        } else {
            s_sc[i] = 0.0f; s_id[i] = 0x7FFFFFFF; s_bx[i] = make_float4(0,0,0,0);
        }
    }
    for (int k = threadIdx.x; k < MAXB; k += blockDim.x) selValid[c*MAXB + k] = 0;
    __syncthreads();

    for (int k = 0; k < MAXB; ++k) {
        // argmax(s) with tie -> lowest ORIGINAL box index (matches jnp.argmax over N)
        float bs = 0.0f; int bid = 0x7FFFFFFF; int bsl = -1;
        for (int i = threadIdx.x; i < CAP; i += blockDim.x) {
            float s = s_sc[i];
            if (s > 0.0f) {
                int id = s_id[i];
                if (s > bs || (s == bs && id < bid)) { bs = s; bid = id; bsl = i; }
            }
        }
        for (int off = 32; off >= 1; off >>= 1) {
            float os = __shfl_xor(bs, off);
            int  oid = __shfl_xor(bid, off);
            int  osl = __shfl_xor(bsl, off);
            if (os > bs || (os == bs && oid < bid)) { bs = os; bid = oid; bsl = osl; }
        }
        int lane = threadIdx.x & 63, wid = threadIdx.x >> 6;
        if (lane == 0) { red_s[wid] = bs; red_i[wid] = bid; red_sl[wid] = bsl; }
        __syncthreads();
        if (threadIdx.x == 0) {
            bs = red_s[0]; bid = red_i[0]; bsl = red_sl[0];
            for (int w = 1; w < 4; ++w) {
                float os = red_s[w]; int oid = red_i[w]; int osl = red_sl[w];
                if (os > bs || (os == bs && oid < bid)) { bs = os; bid = oid; bsl = osl; }
            }
            if (bs > 0.0f) {
                g_stop = 0; g_idx = bid; g_box = s_bx[bsl];
                selBox[c*MAXB + k]   = s_bx[bsl];
                selValid[c*MAXB + k] = 1;
            } else {
                g_stop = 1;
            }
        }
        __syncthreads();
        if (g_stop) break;   // remaining iterations are all invalid => never drawn

        float4 B = g_box; int bidx = g_idx;
        float a0 = (B.z - B.x) * (B.w - B.y);
        for (int i = threadIdx.x; i < CAP; i += blockDim.x) {
            float s = s_sc[i];
            if (s > 0.0f) {
                float4 A = s_bx[i];
                float x1 = fmaxf(B.x, A.x);
                float y1 = fmaxf(B.y, A.y);
                float x2 = fminf(B.z, A.z);
                float y2 = fminf(B.w, A.w);
                float inter = fmaxf(x2 - x1, 0.0f) * fmaxf(y2 - y1, 0.0f);
                float a1 = (A.z - A.x) * (A.w - A.y);
                float uni = a0 + a1 - inter;
                float iou = (uni > 0.0f) ? (inter / uni) : 0.0f;
                if (iou > NMS_T_ || s_id[i] == bidx) s_sc[i] = 0.0f;
            }
        }
        __syncthreads();
    }
}

// ---------------- draw edges ----------------
__device__ __forceinline__ int to_px(float v) {
    float r = rintf(v * 831.0f);           // jnp.round = half-to-even
    r = fminf(fmaxf(r, 0.0f), 831.0f);     // clip AFTER round
    return (int)r;
}

__global__ void draw_kernel(const float4* __restrict__ selBox, const int* __restrict__ selValid,
                            float* __restrict__ out)
{
    int b = blockIdx.x;
    if (!selValid[b]) return;
    float4 B = selBox[b];
    int r1 = to_px(B.x), c1 = to_px(B.y), r2 = to_px(B.z), c2 = to_px(B.w);
    for (int i = threadIdx.x; i <= c2 - c1; i += blockDim.x) {
        out[r1*IMG + c1 + i] = 1.0f;
        out[r2*IMG + c1 + i] = 1.0f;
    }
    for (int i = threadIdx.x; i <= r2 - r1; i += blockDim.x) {
        out[(r1 + i)*IMG + c1] = 1.0f;
        out[(r1 + i)*IMG + c2] = 1.0f;
    }
}

extern "C" void kernel_launch(void* const* d_in, const int* in_sizes, int n_in,
                              void* d_out, int out_size, void* d_ws, size_t ws_size,
                              hipStream_t stream)
{
    const float* in      = (const float*)d_in[0];
    const float* anchors = (const float*)d_in[1];
    float* out           = (float*)d_out;

    char* ws = (char*)d_ws;
    size_t off = 0;
    int*    cnt       = (int*)(ws + off);    off += 1024;                       // 80 ints, padded
    float4* candBox   = (float4*)(ws + off); off += (size_t)NC*CAP*sizeof(float4);
    float*  candScore = (float*)(ws + off);  off += (size_t)NC*CAP*sizeof(float);
    int*    candIdx   = (int*)(ws + off);    off += (size_t)NC*CAP*sizeof(int);
    float4* selBox    = (float4*)(ws + off); off += (size_t)NC*MAXB*sizeof(float4);
    int*    selValid  = (int*)(ws + off);    off += (size_t)NC*MAXB*sizeof(int);

    hipMemsetAsync(cnt, 0, NC*sizeof(int), stream);
    hipMemsetAsync(out, 0, (size_t)IMG*IMG*sizeof(float), stream);

    decode_kernel<<<(NBOX + 255)/256, 256, 0, stream>>>(in, anchors, cnt, candBox, candScore, candIdx);
    nms_kernel<<<NC, 256, 0, stream>>>(cnt, candBox, candScore, candIdx, selBox, selValid);
    draw_kernel<<<NC*MAXB, 128, 0, stream>>>(selBox, selValid, out);
}

// Round 2
// 157.566 us; speedup vs baseline: 2.0075x; 2.0075x over previous
//
#include <hip/hip_runtime.h>
#include <math.h>

#define G       104
#define NBA     9
#define NC      80
#define NBOX    (G*G*NBA)      // 97344
#define CH      (5+NC)         // 85
#define DET_T_  0.02f
#define NMS_T_  0.3f
#define MAXB    50
#define CAP     2048
#define IMG     832
#define CSTRIDE 16             // pad class counters to 64B (separate L2 lines)
#define DB      128            // decode boxes per block

__device__ __forceinline__ float sigmoidf_(float x) { return 1.0f / (1.0f + expf(-x)); }

// ---------------- decode + per-class compaction (LDS-staged, coalesced) ----------------
__global__ __launch_bounds__(DB) void decode_kernel(const float* __restrict__ in,
        const float* __restrict__ anchors, int* __restrict__ cnt,
        float4* __restrict__ candBox, float* __restrict__ candScore, int* __restrict__ candIdx)
{
    __shared__ float lds[DB * CH];   // 43,520 B
    const int tid = threadIdx.x;
    const int base = blockIdx.x * (DB * CH);      // NBOX*CH = 8,274,240 fits int
    int nfl = NBOX * CH - base;
    if (nfl > DB * CH) nfl = DB * CH;

    // coalesced staged load (block base is 16B aligned: DB*CH*4 = 43520)
    int nv4 = nfl >> 2;
    const float4* gin4 = (const float4*)(in + base);
    for (int i = tid; i < nv4; i += DB) ((float4*)lds)[i] = gin4[i];
    for (int i = (nv4 << 2) + tid; i < nfl; i += DB) lds[i] = in[base + i];
    __syncthreads();

    int n = blockIdx.x * DB + tid;
    if (n >= NBOX) return;
    const float* p = lds + tid * CH;   // stride 85 floats: gcd(85,32)=1 -> 2-way alias, free

    // softmax over p[5..84]: exp(x - max) / sum  (exact reference op order)
    float m = -INFINITY;
    for (int i = 0; i < NC; ++i) m = fmaxf(m, p[5 + i]);
    float sum = 0.0f;
    for (int i = 0; i < NC; ++i) sum += expf(p[5 + i] - m);
    float obj = sigmoidf_(p[4]);

    // first-max argmax over s_i = obj * (e_i / sum)
    float best = -1.0f; int bcls = 0;
    for (int i = 0; i < NC; ++i) {
        float e = expf(p[5 + i] - m);
        float s = obj * (e / sum);
        if (s > best) { best = s; bcls = i; }
    }

    if (best > DET_T_) {
        int a  = n % NBA;
        int t  = n / NBA;
        int gx = t % G;
        int gy = t / G;
        float bx = (sigmoidf_(p[0]) + (float)gx) / (float)G;
        float by = (sigmoidf_(p[1]) + (float)gy) / (float)G;
        float bw = expf(p[2]) * anchors[2*a + 0] / (float)G;
        float bh = expf(p[3]) * anchors[2*a + 1] / (float)G;
        float4 box = make_float4(bx - bw / 2.0f, by - bh / 2.0f,
                                 bx + bw / 2.0f, by + bh / 2.0f);
        int pos = atomicAdd(&cnt[bcls * CSTRIDE], 1);
        if (pos < CAP) {
            int slot = bcls * CAP + pos;
            candBox[slot]   = box;
            candScore[slot] = best;
            candIdx[slot]   = n;
        }
    }
}

// ---------------- per-class greedy NMS: register-resident, fused suppress+argmax ----------------
__global__ __launch_bounds__(256) void nms_kernel(const int* __restrict__ cnt,
    const float4* __restrict__ candBox, const float* __restrict__ candScore,
    const int* __restrict__ candIdx, float4* __restrict__ selBox, int* __restrict__ selValid)
{
    __shared__ float  red_s[4];
    __shared__ int    red_id[4];
    __shared__ float4 red_bx[4];

    const int c = blockIdx.x;
    int count = cnt[c * CSTRIDE]; if (count > CAP) count = CAP;

    // each thread owns 8 slots in registers
    float  sc[8]; int id[8]; float4 bx[8];
#pragma unroll
    for (int j = 0; j < 8; ++j) {
        int i = threadIdx.x + j * 256;
        if (i < count) {
            sc[j] = candScore[c*CAP + i];
            bx[j] = candBox[c*CAP + i];
            id[j] = candIdx[c*CAP + i];
        } else {
            sc[j] = 0.0f; id[j] = 0x7FFFFFFF; bx[j] = make_float4(0,0,0,0);
        }
    }
    for (int k = threadIdx.x; k < MAXB; k += 256) selValid[c*MAXB + k] = 0;
    // no barrier needed here: selValid[k]=1 writes happen after the first __syncthreads below

    float4 W = make_float4(0,0,0,0);   // current winner box
    int    wbid = -1;                  // current winner original index

    for (int k = 0; k < MAXB; ++k) {
        float bs = 0.0f; int bid = 0x7FFFFFFF; float4 bb = make_float4(0,0,0,0);

        if (k == 0) {
#pragma unroll
            for (int j = 0; j < 8; ++j) {
                float s = sc[j];
                if (s > 0.0f && (s > bs || (s == bs && id[j] < bid))) {
                    bs = s; bid = id[j]; bb = bx[j];
                }
            }
        } else {
            // fused: suppress vs W, then consider survivor for next max (= sequential semantics)
            float a0 = (W.z - W.x) * (W.w - W.y);
#pragma unroll
            for (int j = 0; j < 8; ++j) {
                float s = sc[j];
                if (s > 0.0f) {
                    float4 A = bx[j];
                    float x1 = fmaxf(W.x, A.x), y1 = fmaxf(W.y, A.y);
                    float x2 = fminf(W.z, A.z), y2 = fminf(W.w, A.w);
                    float inter = fmaxf(x2 - x1, 0.0f) * fmaxf(y2 - y1, 0.0f);
                    float a1 = (A.z - A.x) * (A.w - A.y);
                    float uni = a0 + a1 - inter;
                    float iou = (uni > 0.0f) ? (inter / uni) : 0.0f;
                    if (iou > NMS_T_ || id[j] == wbid) { sc[j] = 0.0f; s = 0.0f; }
                    if (s > 0.0f && (s > bs || (s == bs && id[j] < bid))) {
                        bs = s; bid = id[j]; bb = bx[j];
                    }
                }
            }
        }

        // wave reduce (64 lanes), carrying the box
#pragma unroll
        for (int off = 32; off >= 1; off >>= 1) {
            float os  = __shfl_xor(bs, off);
            int   oid = __shfl_xor(bid, off);
            float ox  = __shfl_xor(bb.x, off);
            float oy  = __shfl_xor(bb.y, off);
            float oz  = __shfl_xor(bb.z, off);
            float ow  = __shfl_xor(bb.w, off);
            if (os > bs || (os == bs && os > 0.0f && oid < bid)) {
                bs = os; bid = oid; bb = make_float4(ox, oy, oz, ow);
            }
        }
        int wv = threadIdx.x >> 6;
        if ((threadIdx.x & 63) == 0) { red_s[wv] = bs; red_id[wv] = bid; red_bx[wv] = bb; }
        __syncthreads();

        // all threads redundantly combine the 4 wave winners (LDS broadcast reads)
        float gbs = red_s[0]; int gbid = red_id[0]; float4 gbx = red_bx[0];
#pragma unroll
        for (int w = 1; w < 4; ++w) {
            float os = red_s[w]; int oid = red_id[w];
            if (os > gbs || (os == gbs && os > 0.0f && oid < gbid)) {
                gbs = os; gbid = oid; gbx = red_bx[w];
            }
        }
        __syncthreads();   // protect red_* reuse next iteration

        if (gbs <= 0.0f) break;   // uniform across block; rest of picks invalid => never drawn

        if (threadIdx.x == 0) {
            selBox[c*MAXB + k]   = gbx;
            selValid[c*MAXB + k] = 1;
        }
        W = gbx; wbid = gbid;
    }
}

// ---------------- draw edges ----------------
__device__ __forceinline__ int to_px(float v) {
    float r = rintf(v * 831.0f);           // jnp.round = half-to-even
    r = fminf(fmaxf(r, 0.0f), 831.0f);     // clip AFTER round
    return (int)r;
}

__global__ void draw_kernel(const float4* __restrict__ selBox, const int* __restrict__ selValid,
                            float* __restrict__ out)
{
    int b = blockIdx.x;
    if (!selValid[b]) return;
    float4 B = selBox[b];
    int r1 = to_px(B.x), c1 = to_px(B.y), r2 = to_px(B.z), c2 = to_px(B.w);
    for (int i = threadIdx.x; i <= c2 - c1; i += blockDim.x) {
        out[r1*IMG + c1 + i] = 1.0f;
        out[r2*IMG + c1 + i] = 1.0f;
    }
    for (int i = threadIdx.x; i <= r2 - r1; i += blockDim.x) {
        out[(r1 + i)*IMG + c1] = 1.0f;
        out[(r1 + i)*IMG + c2] = 1.0f;
    }
}

extern "C" void kernel_launch(void* const* d_in, const int* in_sizes, int n_in,
                              void* d_out, int out_size, void* d_ws, size_t ws_size,
                              hipStream_t stream)
{
    const float* in      = (const float*)d_in[0];
    const float* anchors = (const float*)d_in[1];
    float* out           = (float*)d_out;

    char* ws = (char*)d_ws;
    size_t off = 0;
    int*    cnt       = (int*)(ws + off);    off += (size_t)NC*CSTRIDE*sizeof(int);
    float4* candBox   = (float4*)(ws + off); off += (size_t)NC*CAP*sizeof(float4);
    float*  candScore = (float*)(ws + off);  off += (size_t)NC*CAP*sizeof(float);
    int*    candIdx   = (int*)(ws + off);    off += (size_t)NC*CAP*sizeof(int);
    float4* selBox    = (float4*)(ws + off); off += (size_t)NC*MAXB*sizeof(float4);
    int*    selValid  = (int*)(ws + off);    off += (size_t)NC*MAXB*sizeof(int);

    hipMemsetAsync(cnt, 0, (size_t)NC*CSTRIDE*sizeof(int), stream);
    hipMemsetAsync(out, 0, (size_t)IMG*IMG*sizeof(float), stream);

    decode_kernel<<<(NBOX + DB - 1)/DB, DB, 0, stream>>>(in, anchors, cnt, candBox, candScore, candIdx);
    nms_kernel<<<NC, 256, 0, stream>>>(cnt, candBox, candScore, candIdx, selBox, selValid);
    draw_kernel<<<NC*MAXB, 128, 0, stream>>>(selBox, selValid, out);
}